// Round 4
// baseline (5194.530 us; speedup 1.0000x reference)
//
#include <hip/hip_runtime.h>
#include <hip/hip_bf16.h>

typedef unsigned short u16;
typedef short bf16x8 __attribute__((ext_vector_type(8)));
typedef float f32x4 __attribute__((ext_vector_type(4)));

#define BB 2
#define SS 2048
#define DD 2048
#define HH 16
#define HDIM 128
#define HIDF 5632
#define MROWS (BB*SS)   // 4096

__device__ __forceinline__ float bf2f(u16 x){
  union { unsigned u; float f; } c; c.u = ((unsigned)x) << 16; return c.f;
}
__device__ __forceinline__ u16 f2bf(float f){
  union { float f; unsigned u; } c; c.f = f;
  unsigned u = c.u;
  u += 0x7FFFu + ((u >> 16) & 1u);   // RNE
  return (u16)(u >> 16);
}
__device__ __forceinline__ float clamp_sig(float v){
  // NaN -> +8192 (diagnostic signal); legit values never reach +-8192
  return fmaxf(fminf(v, 8192.f), -8192.f);
}

// Per-block input-dtype detection: scan 2048 u16 of a weight tensor.
// bf16 weights (sigma=0.02): exponent field always < 0x90.
// fp32 data read as u16: even halves are mantissa garbage, ~44% >= 0x90.
__device__ int detect_fp32(const u16* __restrict__ probe){
  __shared__ int sflag;
  if (threadIdx.x == 0) sflag = 0;
  __syncthreads();
  int bad = 0;
  #pragma unroll
  for (int i = 0; i < 8; i++){
    u16 v = probe[threadIdx.x * 8 + i];
    int e = (v >> 7) & 0xFF;
    bad += (e >= 0x90);
  }
  if (bad) atomicAdd(&sflag, bad);
  __syncthreads();
  return sflag > 16;
}

// ---------------- RMSNorm: row of 2048 -> bf16 out ----------------
__global__ __launch_bounds__(256) void rmsnorm_k(const void* __restrict__ src,
                                                 const void* __restrict__ w,
                                                 u16* __restrict__ y,
                                                 const u16* __restrict__ probe,
                                                 int src_probe){
  int f = detect_fp32(probe);
  int sdt = src_probe ? f : 0;
  int row = blockIdx.x, t = threadIdx.x;
  float v[8];
  if (sdt){
    const float* xr = (const float*)src + (size_t)row * DD + t * 8;
    #pragma unroll
    for (int i = 0; i < 8; i++) v[i] = xr[i];
  } else {
    const u16* xr = (const u16*)src + (size_t)row * DD + t * 8;
    uint4 pk = *(const uint4*)xr;
    u16* pv = (u16*)&pk;
    #pragma unroll
    for (int i = 0; i < 8; i++) v[i] = bf2f(pv[i]);
  }
  float ss = 0.f;
  #pragma unroll
  for (int i = 0; i < 8; i++) ss += v[i] * v[i];
  #pragma unroll
  for (int off = 32; off > 0; off >>= 1) ss += __shfl_down(ss, off, 64);
  __shared__ float red[4];
  if ((t & 63) == 0) red[t >> 6] = ss;
  __syncthreads();
  if (t == 0){
    float s = red[0] + red[1] + red[2] + red[3];
    red[0] = rsqrtf(s / (float)DD + 1e-5f);
  }
  __syncthreads();
  float r = red[0];
  float wf[8];
  if (f){
    const float* wp = (const float*)w + t * 8;
    #pragma unroll
    for (int i = 0; i < 8; i++) wf[i] = wp[i];
  } else {
    const u16* wp = (const u16*)w + t * 8;
    uint4 wk = *(const uint4*)wp;
    u16* pw = (u16*)&wk;
    #pragma unroll
    for (int i = 0; i < 8; i++) wf[i] = bf2f(pw[i]);
  }
  u16 ob[8];
  #pragma unroll
  for (int i = 0; i < 8; i++){
    float yn = v[i] * r;
    if (!f) yn = bf2f(f2bf(yn));   // bf16 world: ref casts to bf16 before *w
    ob[i] = f2bf(yn * wf[i]);
  }
  *(uint4*)(y + (size_t)row * DD + t * 8) = *(uint4*)ob;
}

// ---------------- RoPE in-place on [B,S,H,HD] (ws, bf16) ----------------
__global__ __launch_bounds__(256) void rope_k(u16* __restrict__ x,
                                              const void* __restrict__ cosb,
                                              const void* __restrict__ sinb,
                                              const u16* __restrict__ probe){
  int f = detect_fp32(probe);
  size_t i = (size_t)blockIdx.x * 256 + threadIdx.x;  // pair index
  int p = (int)(i & 63);
  int s = (int)((i >> 10) & (SS - 1));
  u16* px = x + i * 2;
  float a = bf2f(px[0]), b = bf2f(px[1]);
  float c, sn;
  if (f){
    c  = ((const float*)cosb)[s * 64 + p];
    sn = ((const float*)sinb)[s * 64 + p];
  } else {
    c  = bf2f(((const u16*)cosb)[s * 64 + p]);
    sn = bf2f(((const u16*)sinb)[s * 64 + p]);
  }
  px[0] = f2bf(a * c - b * sn);
  px[1] = f2bf(a * sn + b * c);
}

// ---- B staging helper: stage B[k0..k0+32][n0..n0+128] (row-major [K][N])
// into Bs[n][k] (128 rows x 32 u16). Dual dtype. ----
__device__ __forceinline__ void stage_B(const void* __restrict__ B, u16* Bs,
                                        int k0, int n0, int N, int f, int t){
  if (!f){
    const u16* Bh = (const u16*)B;
    #pragma unroll
    for (int i = 0; i < 2; i++){
      int c = t + 256 * i;
      int kr = c >> 4, cg = c & 15;
      uint4 pk = *(const uint4*)(Bh + (size_t)(k0 + kr) * N + n0 + cg * 8);
      u16* tv = (u16*)&pk;
      #pragma unroll
      for (int j = 0; j < 8; j++) Bs[(cg * 8 + j) * 32 + kr] = tv[j];
    }
  } else {
    const float* Bf = (const float*)B;
    #pragma unroll
    for (int i = 0; i < 2; i++){
      int c = t + 256 * i;
      int kr = c >> 4, cg = c & 15;
      const float* gp = Bf + (size_t)(k0 + kr) * N + n0 + cg * 8;
      float4 x0 = *(const float4*)gp;
      float4 x1 = *(const float4*)(gp + 4);
      u16* d = Bs + (cg * 8) * 32 + kr;
      d[0*32] = f2bf(x0.x); d[1*32] = f2bf(x0.y);
      d[2*32] = f2bf(x0.z); d[3*32] = f2bf(x0.w);
      d[4*32] = f2bf(x1.x); d[5*32] = f2bf(x1.y);
      d[6*32] = f2bf(x1.z); d[7*32] = f2bf(x1.w);
    }
  }
}

// ---------------- MFMA GEMM: C[M,N] = A[M,K] @ B[K,N] (+Res) ----------------
// A: bf16 ws. B: d_in weight, row-major [K][N], dual-dtype.
// out_probe: if set and inputs are fp32, C is written as fp32 (d_out case).
template<int EPI>
__global__ __launch_bounds__(256) void gemm_bn(const u16* __restrict__ A,
                                               const void* __restrict__ B,
                                               void* __restrict__ C,
                                               const void* __restrict__ Res,
                                               const u16* __restrict__ probe,
                                               int M, int N, int K,
                                               int res_probe, int out_probe){
  int f = detect_fp32(probe);
  __shared__ u16 As[128 * 32];
  __shared__ u16 Bs[128 * 32];
  int t = threadIdx.x;
  int l = t & 63, w = t >> 6;
  int wm = w >> 1, wn = w & 1;
  int m0 = blockIdx.y * 128, n0 = blockIdx.x * 128;
  const int lrow = l & 15, lq = l >> 4;

  f32x4 acc[4][4];
  #pragma unroll
  for (int i = 0; i < 4; i++)
    #pragma unroll
    for (int j = 0; j < 4; j++) acc[i][j] = (f32x4){0.f, 0.f, 0.f, 0.f};

  for (int k0 = 0; k0 < K; k0 += 32){
    #pragma unroll
    for (int i = 0; i < 2; i++){
      int c = t + 256 * i;
      int row = c >> 2, kp = (c & 3) * 8;
      *(uint4*)(As + (size_t)c * 8) =
          *(const uint4*)(A + (size_t)(m0 + row) * K + k0 + kp);
    }
    stage_B(B, Bs, k0, n0, N, f, t);
    __syncthreads();
    bf16x8 aF[4], bF[4];
    #pragma unroll
    for (int mi = 0; mi < 4; mi++)
      aF[mi] = *(const bf16x8*)(As + (wm * 64 + mi * 16 + lrow) * 32 + lq * 8);
    #pragma unroll
    for (int ni = 0; ni < 4; ni++)
      bF[ni] = *(const bf16x8*)(Bs + (wn * 64 + ni * 16 + lrow) * 32 + lq * 8);
    #pragma unroll
    for (int mi = 0; mi < 4; mi++)
      #pragma unroll
      for (int ni = 0; ni < 4; ni++)
        acc[mi][ni] = __builtin_amdgcn_mfma_f32_16x16x32_bf16(aF[mi], bF[ni], acc[mi][ni], 0, 0, 0);
    __syncthreads();
  }

  int rdt = res_probe ? f : 0;
  int odt = out_probe ? f : 0;
  #pragma unroll
  for (int mi = 0; mi < 4; mi++){
    #pragma unroll
    for (int ni = 0; ni < 4; ni++){
      #pragma unroll
      for (int r = 0; r < 4; r++){
        int row = m0 + wm * 64 + mi * 16 + lq * 4 + r;
        int col = n0 + wn * 64 + ni * 16 + lrow;
        float v = acc[mi][ni][r];
        if (EPI == 1){
          if (rdt) v += ((const float*)Res)[(size_t)row * N + col];
          else     v += bf2f(((const u16*)Res)[(size_t)row * N + col]);
        }
        v = clamp_sig(v);
        if (odt) ((float*)C)[(size_t)row * N + col] = v;
        else     ((u16*)C)[(size_t)row * N + col] = f2bf(v);
      }
    }
  }
}

// ---------------- Dual-B MFMA GEMM with SwiGLU epilogue ----------------
__global__ __launch_bounds__(256) void gemm_ffn(const u16* __restrict__ A,
                                                const void* __restrict__ B1,
                                                const void* __restrict__ B3,
                                                u16* __restrict__ G,
                                                const u16* __restrict__ probe,
                                                int M, int N, int K){
  int f = detect_fp32(probe);
  __shared__ u16 As[128 * 32];
  __shared__ u16 B1s[128 * 32];
  __shared__ u16 B3s[128 * 32];
  int t = threadIdx.x;
  int l = t & 63, w = t >> 6;
  int wm = w >> 1, wn = w & 1;
  int m0 = blockIdx.y * 128, n0 = blockIdx.x * 128;
  const int lrow = l & 15, lq = l >> 4;

  f32x4 acc1[4][4], acc3[4][4];
  #pragma unroll
  for (int i = 0; i < 4; i++)
    #pragma unroll
    for (int j = 0; j < 4; j++){
      acc1[i][j] = (f32x4){0.f, 0.f, 0.f, 0.f};
      acc3[i][j] = (f32x4){0.f, 0.f, 0.f, 0.f};
    }

  for (int k0 = 0; k0 < K; k0 += 32){
    #pragma unroll
    for (int i = 0; i < 2; i++){
      int c = t + 256 * i;
      int row = c >> 2, kp = (c & 3) * 8;
      *(uint4*)(As + (size_t)c * 8) =
          *(const uint4*)(A + (size_t)(m0 + row) * K + k0 + kp);
    }
    stage_B(B1, B1s, k0, n0, N, f, t);
    stage_B(B3, B3s, k0, n0, N, f, t);
    __syncthreads();
    bf16x8 aF[4], b1F[4], b3F[4];
    #pragma unroll
    for (int mi = 0; mi < 4; mi++)
      aF[mi] = *(const bf16x8*)(As + (wm * 64 + mi * 16 + lrow) * 32 + lq * 8);
    #pragma unroll
    for (int ni = 0; ni < 4; ni++){
      b1F[ni] = *(const bf16x8*)(B1s + (wn * 64 + ni * 16 + lrow) * 32 + lq * 8);
      b3F[ni] = *(const bf16x8*)(B3s + (wn * 64 + ni * 16 + lrow) * 32 + lq * 8);
    }
    #pragma unroll
    for (int mi = 0; mi < 4; mi++)
      #pragma unroll
      for (int ni = 0; ni < 4; ni++){
        acc1[mi][ni] = __builtin_amdgcn_mfma_f32_16x16x32_bf16(aF[mi], b1F[ni], acc1[mi][ni], 0, 0, 0);
        acc3[mi][ni] = __builtin_amdgcn_mfma_f32_16x16x32_bf16(aF[mi], b3F[ni], acc3[mi][ni], 0, 0, 0);
      }
    __syncthreads();
  }

  #pragma unroll
  for (int mi = 0; mi < 4; mi++){
    #pragma unroll
    for (int ni = 0; ni < 4; ni++){
      #pragma unroll
      for (int r = 0; r < 4; r++){
        int row = m0 + wm * 64 + mi * 16 + lq * 4 + r;
        int col = n0 + wn * 64 + ni * 16 + lrow;
        float g1 = acc1[mi][ni][r];
        float g3 = acc3[mi][ni][r];
        if (!f){ g1 = bf2f(f2bf(g1)); g3 = bf2f(f2bf(g3)); }
        float s  = g1 / (1.f + __expf(-g1));
        if (!f) s = bf2f(f2bf(s));
        float pr = s * g3;
        G[(size_t)row * N + col] = f2bf(clamp_sig(pr));
      }
    }
  }
}

// ---------------- flash attention (VALU fp32, online softmax) ----------------
__global__ __launch_bounds__(256) void attn_k(const u16* __restrict__ Qg,
                                              const u16* __restrict__ Kg,
                                              const u16* __restrict__ Vg,
                                              u16* __restrict__ Og){
  __shared__ float Qs[32][132];
  __shared__ float Ks[32][132];
  __shared__ float Vs[32][132];
  __shared__ float Sb[32][36];
  __shared__ float alpha[32], mrun[32], lrun[32];

  int t = threadIdx.x;
  int bid = blockIdx.x;
  int qt = bid & 63;
  int h  = (bid >> 6) & 15;
  int b  = bid >> 10;
  const size_t base = ((size_t)b * SS) * DD + (size_t)h * HDIM;
  int q0 = qt * 32;
  const float scale = 0.08838834764831845f;  // 1/sqrt(128)

  for (int i = t; i < 32 * 64; i += 256){
    int r = i >> 6, c2 = (i & 63) * 2;
    const u16* p = Qg + base + (size_t)(q0 + r) * DD + c2;
    Qs[r][c2]     = bf2f(p[0]) * scale;
    Qs[r][c2 + 1] = bf2f(p[1]) * scale;
  }
  if (t < 32){ mrun[t] = -1e30f; lrun[t] = 0.f; }

  int qr = t >> 3, dc = (t & 7) * 16;
  float o[16];
  #pragma unroll
  for (int i = 0; i < 16; i++) o[i] = 0.f;
  __syncthreads();

  for (int kt = 0; kt < 64; kt++){
    int k0 = kt * 32;
    for (int i = t; i < 32 * 64; i += 256){
      int r = i >> 6, c2 = (i & 63) * 2;
      const u16* pk = Kg + base + (size_t)(k0 + r) * DD + c2;
      Ks[r][c2]     = bf2f(pk[0]);
      Ks[r][c2 + 1] = bf2f(pk[1]);
      const u16* pv = Vg + base + (size_t)(k0 + r) * DD + c2;
      Vs[r][c2]     = bf2f(pv[0]);
      Vs[r][c2 + 1] = bf2f(pv[1]);
    }
    __syncthreads();

    {   // scores
      int kc = (t & 7) * 4;
      float a0 = 0.f, a1 = 0.f, a2 = 0.f, a3 = 0.f;
      #pragma unroll 8
      for (int d = 0; d < HDIM; d += 4){
        float4 qv  = *(const float4*)&Qs[qr][d];
        float4 k0v = *(const float4*)&Ks[kc + 0][d];
        float4 k1v = *(const float4*)&Ks[kc + 1][d];
        float4 k2v = *(const float4*)&Ks[kc + 2][d];
        float4 k3v = *(const float4*)&Ks[kc + 3][d];
        a0 += qv.x*k0v.x + qv.y*k0v.y + qv.z*k0v.z + qv.w*k0v.w;
        a1 += qv.x*k1v.x + qv.y*k1v.y + qv.z*k1v.z + qv.w*k1v.w;
        a2 += qv.x*k2v.x + qv.y*k2v.y + qv.z*k2v.z + qv.w*k2v.w;
        a3 += qv.x*k3v.x + qv.y*k3v.y + qv.z*k3v.z + qv.w*k3v.w;
      }
      Sb[qr][kc + 0] = a0; Sb[qr][kc + 1] = a1;
      Sb[qr][kc + 2] = a2; Sb[qr][kc + 3] = a3;
    }
    __syncthreads();

    if (t < 32){  // online softmax per row
      float m_old = mrun[t];
      float mt = m_old;
      #pragma unroll
      for (int j = 0; j < 32; j++) mt = fmaxf(mt, Sb[t][j]);
      float a = __expf(m_old - mt);
      float s = 0.f;
      #pragma unroll
      for (int j = 0; j < 32; j++){
        float p = __expf(Sb[t][j] - mt);
        Sb[t][j] = p; s += p;
      }
      lrun[t] = lrun[t] * a + s;
      mrun[t] = mt;
      alpha[t] = a;
    }
    __syncthreads();

    {   // O = O*alpha + P @ V
      float aa = alpha[qr];
      #pragma unroll
      for (int i = 0; i < 16; i++) o[i] *= aa;
      for (int kk = 0; kk < 32; kk++){
        float p = Sb[qr][kk];
        float4 v0 = *(const float4*)&Vs[kk][dc + 0];
        float4 v1 = *(const float4*)&Vs[kk][dc + 4];
        float4 v2 = *(const float4*)&Vs[kk][dc + 8];
        float4 v3 = *(const float4*)&Vs[kk][dc + 12];
        o[0]  += p*v0.x; o[1]  += p*v0.y; o[2]  += p*v0.z; o[3]  += p*v0.w;
        o[4]  += p*v1.x; o[5]  += p*v1.y; o[6]  += p*v1.z; o[7]  += p*v1.w;
        o[8]  += p*v2.x; o[9]  += p*v2.y; o[10] += p*v2.z; o[11] += p*v2.w;
        o[12] += p*v3.x; o[13] += p*v3.y; o[14] += p*v3.z; o[15] += p*v3.w;
      }
    }
    __syncthreads();
  }

  float inv = 1.f / fmaxf(lrun[qr], 1e-30f);
  u16 ob[16];
  #pragma unroll
  for (int i = 0; i < 16; i++) ob[i] = f2bf(clamp_sig(o[i] * inv));
  u16* po = Og + base + (size_t)(q0 + qr) * DD + dc;
  *(uint4*)(po)     = *(const uint4*)(ob);
  *(uint4*)(po + 8) = *(const uint4*)(ob + 8);
}

extern "C" void kernel_launch(void* const* d_in, const int* in_sizes, int n_in,
                              void* d_out, int out_size, void* d_ws, size_t ws_size,
                              hipStream_t stream){
  (void)in_sizes; (void)n_in; (void)out_size; (void)ws_size;
  const void* x   = d_in[0];
  const void* fc  = d_in[1];
  const void* fs  = d_in[2];
  const void* wq  = d_in[3];
  const void* wk  = d_in[4];
  const void* wv  = d_in[5];
  const void* wo  = d_in[6];
  const void* w1  = d_in[7];
  const void* w2  = d_in[8];
  const void* w3  = d_in[9];
  const void* anw = d_in[10];
  const void* fnw = d_in[11];
  const u16* probe = (const u16*)wq;   // dtype probe tensor
  void* out = d_out;

  // ---- workspace layout (total ~84 MB) ----
  char* ws = (char*)d_ws;
  size_t off = 0;
  auto alloc = [&](size_t bytes) -> u16* {
    u16* p = (u16*)(ws + off);
    off += (bytes + 255) & ~(size_t)255;
    return p;
  };
  const size_t SZ_MD = (size_t)MROWS * DD * 2;      // 16.78 MB

  u16* XN  = alloc(SZ_MD);
  u16* Qb  = alloc(SZ_MD);
  u16* Kb  = alloc(SZ_MD);
  u16* Vb  = alloc(SZ_MD);
  u16* Hb  = alloc(SZ_MD);
  u16* AO  = XN;                 // alias: XN dead when attention output written
  u16* G   = Qb;                 // alias: Q/K/V dead in FFN phase (46.1 <= 50.3 MB)

  // --- attention sub-block ---
  rmsnorm_k<<<MROWS, 256, 0, stream>>>(x, anw, XN, probe, 1);
  gemm_bn<0><<<dim3(16, 32), 256, 0, stream>>>(XN, wq, Qb, nullptr, probe, MROWS, DD, DD, 0, 0);
  gemm_bn<0><<<dim3(16, 32), 256, 0, stream>>>(XN, wk, Kb, nullptr, probe, MROWS, DD, DD, 0, 0);
  gemm_bn<0><<<dim3(16, 32), 256, 0, stream>>>(XN, wv, Vb, nullptr, probe, MROWS, DD, DD, 0, 0);
  rope_k<<<16384, 256, 0, stream>>>(Qb, fc, fs, probe);
  rope_k<<<16384, 256, 0, stream>>>(Kb, fc, fs, probe);
  attn_k<<<2048, 256, 0, stream>>>(Qb, Kb, Vb, AO);
  gemm_bn<1><<<dim3(16, 32), 256, 0, stream>>>(AO, wo, Hb, x, probe, MROWS, DD, DD, 1, 0);

  // --- SwiGLU FFN sub-block ---
  rmsnorm_k<<<MROWS, 256, 0, stream>>>(Hb, fnw, XN, probe, 0);
  gemm_ffn<<<dim3(44, 32), 256, 0, stream>>>(XN, w1, w3, G, probe, MROWS, HIDF, DD);
  gemm_bn<1><<<dim3(16, 32), 256, 0, stream>>>(G, w2, out, Hb, probe, MROWS, DD, HIDF, 0, 1);
}